// Round 4
// baseline (547.547 us; speedup 1.0000x reference)
//
#include <hip/hip_runtime.h>
#include <hip/hip_bf16.h>

#define B_DIM   8192
#define FDIM    2048
#define S_DIM   10000
#define D_DIM   100
#define E_NUM   500000
#define ETA     0.01f

#define DPAD    112          // 7 tiles of 16 disease-cols
#define NT      7            // n-tiles
#define KSTEPS  313          // S padded to 10016 = 313*32
#define KSPLIT  8            // K split across blocks (one chunk per XCD)
#define MROWS   64           // rows per block (4 waves x 16)
#define KBLK    1252         // 10016/8 8-elem k-blocks in Asw

typedef float  f32x4  __attribute__((ext_vector_type(4)));
typedef short  s16x8  __attribute__((ext_vector_type(8)));
typedef __bf16 bf16x8 __attribute__((ext_vector_type(8)));

__device__ inline unsigned short f2bf_bits(float x) {
    unsigned int u = __float_as_uint(x);
    unsigned int r = u + 0x7FFFu + ((u >> 16) & 1u);   // RNE
    return (unsigned short)(r >> 16);
}

// ---------------- scatter edge weights into A[d][s] (fp32) ----------------
__global__ void scatter_kernel(const float* __restrict__ ew,
                               const int* __restrict__ esrc,
                               const int* __restrict__ edst,
                               float* __restrict__ A) {
    int e = blockIdx.x * 256 + threadIdx.x;
    if (e < E_NUM) {
        atomicAdd(&A[(size_t)esrc[e] * S_DIM + edst[e]], ew[e]);
    }
}

// ---- transpose+pad+bf16+swizzle: A[d][s] -> Asw[((s/8)*112 + d)*8 + s%8] ----
__global__ void build_asw_kernel(const float* __restrict__ A,
                                 unsigned short* __restrict__ Asw) {
    int t = blockIdx.x * 256 + threadIdx.x;   // 0 .. 1,121,791  (= KBLK*112*8)
    int kb  = t / 896;                        // 896 = 112*8
    int rem = t - kb * 896;
    int d   = rem >> 3;
    int s   = kb * 8 + (rem & 7);
    float v = (d < D_DIM && s < S_DIM) ? A[d * S_DIM + s] : 0.f;
    Asw[t] = f2bf_bits(v);
}

// ---------------- per-row L2 norm of grad_output ----------------
__global__ void norm_kernel(const float* __restrict__ go, float* __restrict__ g) {
    int wave = threadIdx.x >> 6;
    int lane = threadIdx.x & 63;
    int row  = blockIdx.x * 4 + wave;
    const f32x4* p = (const f32x4*)(go + (size_t)row * FDIM);
    float s = 0.f;
#pragma unroll
    for (int j = 0; j < 8; ++j) {
        f32x4 v = __builtin_nontemporal_load(p + lane + 64 * j);
        s += v[0]*v[0] + v[1]*v[1] + v[2]*v[2] + v[3]*v[3];
    }
#pragma unroll
    for (int off = 32; off; off >>= 1) s += __shfl_xor(s, off);
    if (lane == 0) g[row] = sqrtf(s);
}

// ---------------- GEMM: block K-split, LDS B slab, 2-deep sims prefetch ----------------
__device__ inline s16x8 cvt_a(f32x4 f0, f32x4 f1) {
    bf16x8 abf;
    abf[0] = (__bf16)f0[0]; abf[1] = (__bf16)f0[1];
    abf[2] = (__bf16)f0[2]; abf[3] = (__bf16)f0[3];
    abf[4] = (__bf16)f1[0]; abf[5] = (__bf16)f1[1];
    abf[6] = (__bf16)f1[2]; abf[7] = (__bf16)f1[3];
    return __builtin_bit_cast(s16x8, abf);
}

// grid = 128 rowblocks * 8 ksplits; kb = blockIdx&7 -> one Asw chunk per XCD L2
__global__ __launch_bounds__(256, 4)
void gemm_kernel(const float* __restrict__ sims,
                 const unsigned short* __restrict__ Asw,
                 float* __restrict__ part) {
    __shared__ unsigned short buf[2][3584];   // 2 x 7168 B double-buffered B slab
    const int tid  = threadIdx.x;
    const int wave = tid >> 6;
    const int lane = tid & 63;
    const int lhi  = lane >> 4;               // k-subchunk 0..3
    const int llo  = lane & 15;               // A-row / B-col within tile

    const int kb = blockIdx.x & 7;
    const int rb = blockIdx.x >> 3;
    const int t0 = (KSTEPS * kb) >> 3;
    const int t1 = (KSTEPS * (kb + 1)) >> 3;
    const int nsteps = t1 - t0;

    const int row0 = rb * MROWS + wave * 16;
    const float* srow = sims + (size_t)(row0 + llo) * S_DIM + 8 * lhi;

    f32x4 acc[NT];
#pragma unroll
    for (int n = 0; n < NT; ++n) acc[n] = 0.f;

    // prologue: stage slab t0; preload sims steps t0, t0+1 (always in-bounds: k <= 8800)
    if (tid < 224) {
        const s16x8* src = (const s16x8*)(Asw + (size_t)t0 * 3584 + tid * 16);
        s16x8 v0 = src[0], v1 = src[1];
        *(s16x8*)&buf[0][tid * 16]     = v0;
        *(s16x8*)&buf[0][tid * 16 + 8] = v1;
    }
    f32x4 c0, c1, n0, n1;
    {
        const f32x4* p = (const f32x4*)(srow + t0 * 32);
        c0 = __builtin_nontemporal_load(p);
        c1 = __builtin_nontemporal_load(p + 1);
        const f32x4* q = (const f32x4*)(srow + (t0 + 1) * 32);
        n0 = __builtin_nontemporal_load(q);
        n1 = __builtin_nontemporal_load(q + 1);
    }
    __syncthreads();

    for (int i = 0; i < nsteps; ++i) {
        const int t = t0 + i;
        const int cur = i & 1;

        // (1) issue next-slab global loads early (write to LDS late: T14 split)
        s16x8 sv0, sv1;
        const bool do_stage = (i + 1 < nsteps) && (tid < 224);
        if (do_stage) {
            const s16x8* src = (const s16x8*)(Asw + (size_t)(t + 1) * 3584 + tid * 16);
            sv0 = src[0]; sv1 = src[1];
        }

        // (2) issue sims loads for step t+2 (2-deep pipeline)
        f32x4 m0 = 0.f, m1 = 0.f;
        if (i + 2 < nsteps && (t + 2) * 32 + 8 * lhi <= S_DIM - 8) {
            const f32x4* p = (const f32x4*)(srow + (size_t)(t + 2) * 32);
            m0 = __builtin_nontemporal_load(p);
            m1 = __builtin_nontemporal_load(p + 1);
        }

        // (3) compute on step t from registers + LDS
        const unsigned short* bb = &buf[cur][lhi * 896 + llo * 8];
        s16x8 b0 = *(const s16x8*)(bb);
        s16x8 b1 = *(const s16x8*)(bb + 128);
        s16x8 b2 = *(const s16x8*)(bb + 256);
        s16x8 b3 = *(const s16x8*)(bb + 384);
        s16x8 b4 = *(const s16x8*)(bb + 512);
        s16x8 b5 = *(const s16x8*)(bb + 640);
        s16x8 b6 = *(const s16x8*)(bb + 768);

        s16x8 a = cvt_a(c0, c1);
        acc[0] = __builtin_amdgcn_mfma_f32_16x16x32_bf16(a, b0, acc[0], 0, 0, 0);
        acc[1] = __builtin_amdgcn_mfma_f32_16x16x32_bf16(a, b1, acc[1], 0, 0, 0);
        acc[2] = __builtin_amdgcn_mfma_f32_16x16x32_bf16(a, b2, acc[2], 0, 0, 0);
        acc[3] = __builtin_amdgcn_mfma_f32_16x16x32_bf16(a, b3, acc[3], 0, 0, 0);
        acc[4] = __builtin_amdgcn_mfma_f32_16x16x32_bf16(a, b4, acc[4], 0, 0, 0);
        acc[5] = __builtin_amdgcn_mfma_f32_16x16x32_bf16(a, b5, acc[5], 0, 0, 0);
        acc[6] = __builtin_amdgcn_mfma_f32_16x16x32_bf16(a, b6, acc[6], 0, 0, 0);

        // (4) late LDS write of the next slab, then barrier
        if (do_stage) {
            *(s16x8*)&buf[cur ^ 1][tid * 16]     = sv0;
            *(s16x8*)&buf[cur ^ 1][tid * 16 + 8] = sv1;
        }

        c0 = n0; c1 = n1; n0 = m0; n1 = m1;
        __syncthreads();
    }

    // epilogue: write fp32 partials (each slot written by exactly one block)
    float* pslab = part + (size_t)kb * (B_DIM * D_DIM);
    const int rbase = row0 + lhi * 4;
#pragma unroll
    for (int n = 0; n < NT; ++n) {
        const int col = n * 16 + llo;
        if (col < D_DIM) {
#pragma unroll
            for (int r = 0; r < 4; ++r)
                pslab[(size_t)(rbase + r) * D_DIM + col] = acc[n][r];
        }
    }
}

// ---------------- final: out[i][d] = ETA*g[i]*sum_kb part[kb][i][d] ----------------
__global__ void reduce_kernel(const float* __restrict__ part,
                              const float* __restrict__ g,
                              float* __restrict__ out) {
    int idx = blockIdx.x * 256 + threadIdx.x;
    if (idx < B_DIM * D_DIM) {
        float s = 0.f;
#pragma unroll
        for (int kb = 0; kb < KSPLIT; ++kb)
            s += part[(size_t)kb * (B_DIM * D_DIM) + idx];
        int i = idx / D_DIM;
        out[idx] = ETA * g[i] * s;
    }
}

extern "C" void kernel_launch(void* const* d_in, const int* in_sizes, int n_in,
                              void* d_out, int out_size, void* d_ws, size_t ws_size,
                              hipStream_t stream) {
    const float* grad = (const float*)d_in[0];   // [B, FDIM]
    const float* sims = (const float*)d_in[1];   // [B, S]
    const float* ew   = (const float*)d_in[2];   // [E]
    const int*   esrc = (const int*)d_in[3];     // [E]
    const int*   edst = (const int*)d_in[4];     // [E]
    float* out = (float*)d_out;                  // [B, D]

    char* ws = (char*)d_ws;
    float*          A    = (float*)(ws);                        // 4,000,000 B
    unsigned short* Asw  = (unsigned short*)(ws + (4 << 20));   // 2,243,584 B
    float*          g    = (float*)(ws + (7 << 20));            // 32,768 B
    float*          part = (float*)(ws + (8 << 20));            // 26,214,400 B

    hipMemsetAsync(A, 0, (size_t)D_DIM * S_DIM * sizeof(float), stream);

    scatter_kernel  <<<(E_NUM + 255) / 256, 256, 0, stream>>>(ew, esrc, edst, A);
    build_asw_kernel<<<(KBLK * DPAD * 8) / 256, 256, 0, stream>>>(A, Asw);
    norm_kernel     <<<B_DIM / 4, 256, 0, stream>>>(grad, g);
    gemm_kernel     <<<128 * KSPLIT, 256, 0, stream>>>(sims, Asw, part);
    reduce_kernel   <<<(B_DIM * D_DIM + 255) / 256, 256, 0, stream>>>(part, g, out);
}